// Round 12
// baseline (174.630 us; speedup 1.0000x reference)
//
#include <hip/hip_runtime.h>
#include <stdint.h>

#define CAP 32

typedef unsigned int u32x4 __attribute__((ext_vector_type(4)));
typedef _Float16 half8 __attribute__((ext_vector_type(8)));

static constexpr int BATCH = 2048;
static constexpr int D0 = 4096, D1 = 8192, D2 = 8192, D3 = 4096;
static constexpr int RP = 8192;
static constexpr size_t PREFIX_BYTES = 8u << 20;   // detect prefix

static constexpr int CHUNK16 = 8192;               // u32x4 per 128 KiB chunk
// worst-case (int64 masks) chunk counts — grid sized for these, extra blocks exit
static constexpr int MAXC1 = 2048, MAXC2 = 4096, MAXC3 = 2048;

// ---------------- ws layout (bytes) ----------------
static constexpr size_t OFF_DET   = 0;                               // 2 u32
static constexpr size_t OFF_CNT   = 256;                             // 3*8192 int (atomic -> zero each call)
static constexpr size_t ZERO_BYTES= OFF_CNT + 3ull * RP * 4;         // det+cnt
static constexpr size_t OFF_TB    = ZERO_BYTES;                      // 2*8192 float
static constexpr size_t OFF_RK    = OFF_TB + 2ull * RP * 4;          // 3*8192*CAP int
static constexpr size_t OFF_RW    = OFF_RK + 3ull * RP * CAP * 4;
static constexpr size_t OFF_XT    = OFF_RW + 3ull * RP * CAP * 4;    // half [4096][2048]
static constexpr size_t OFF_H1    = OFF_XT + (size_t)D0 * BATCH * 2; // half [8192][2048]
static constexpr size_t WS_BIG    = OFF_H1 + (size_t)D1 * BATCH * 2; // ~53 MB

__device__ __forceinline__ u32x4 ntload4(const u32x4* p) {
    return __builtin_nontemporal_load(p);
}

// ---------------------------------------------------------------------------
// Mask dtype detection (nonzero-byte position stats over 8MB prefix of m1).
// ---------------------------------------------------------------------------
__global__ __launch_bounds__(256) void detect_kernel(const uint8_t* __restrict__ m,
                                                     unsigned* __restrict__ det) {
    const u32x4* p = (const u32x4*)m;
    const int n16 = (int)(PREFIX_BYTES / 16);
    unsigned c123 = 0, c4 = 0;
    for (int i = blockIdx.x * blockDim.x + threadIdx.x; i < n16; i += gridDim.x * blockDim.x) {
        u32x4 q = ntload4(p + i);
        if ((q.x | q.y | q.z | q.w) == 0u) continue;
        unsigned w4[4] = {q.x, q.y, q.z, q.w};
        for (int t = 0; t < 4; ++t) {
            unsigned v = w4[t];
            if (!v) continue;
            for (int bb = 0; bb < 4; ++bb) {
                if ((v >> (8 * bb)) & 0xFFu) {
                    int pm8 = (t * 4 + bb) & 7;
                    if (pm8 & 3) c123++;
                    else if (pm8 == 4) c4++;
                }
            }
        }
    }
    if (c123) atomicAdd(&det[0], c123);
    if (c4)   atomicAdd(&det[1], c4);
}

__device__ __forceinline__ int decide_mode(const unsigned* det) {
    unsigned c123 = det[0], c4 = det[1];
    if (c123 > 520u) return 0;           // 1-byte elements
    if (c123 > 200u) return 1;           // float32 (word != 0 works)
    return (c4 > 40u) ? 1 : 2;           // int32 vs int64
}

__device__ __forceinline__ int esize_of(int mode) { return mode == 0 ? 1 : (mode == 1 ? 4 : 8); }

// ---------------------------------------------------------------------------
// Barrier-free flat chunk scan (R9 shape: 4 iters x 8 hoisted nt loads).
// Nonzero element e -> global atomic scatter. Lists UNSORTED; sorted later.
// ---------------------------------------------------------------------------
__device__ __forceinline__ void scat(int e, int flog2, const float* W,
                                     int* cnt, int* rk, float* rw) {
    int row = e >> flog2;
    int col = e & ((1 << flog2) - 1);
    int pos = atomicAdd(&cnt[row], 1);
    if (pos < CAP) {
        rk[(size_t)row * CAP + pos] = col;
        rw[(size_t)row * CAP + pos] = __builtin_nontemporal_load(&W[(size_t)e]);
    }
}

template<int FLOG2>
__device__ __forceinline__ void scan_chunk(const void* __restrict__ mask, const float* __restrict__ W,
                                           int chunk, int mode,
                                           int* cnt, int* rk, float* rw) {
    const u32x4* q4 = (const u32x4*)mask;
    const int base16 = chunk * CHUNK16;
    #pragma unroll 1
    for (int it = 0; it < 4; ++it) {
        const u32x4* p = q4 + base16 + it * 2048 + threadIdx.x;
        u32x4 v[8];
        #pragma unroll
        for (int t = 0; t < 8; ++t) v[t] = ntload4(p + t * 256);
        #pragma unroll
        for (int t = 0; t < 8; ++t) {
            u32x4 q = v[t];
            if ((q.x | q.y | q.z | q.w) == 0u) continue;
            int i16 = base16 + it * 2048 + t * 256 + (int)threadIdx.x;
            if (mode == 1) {
                int eb = i16 << 2;
                if (q.x) scat(eb + 0, FLOG2, W, cnt, rk, rw);
                if (q.y) scat(eb + 1, FLOG2, W, cnt, rk, rw);
                if (q.z) scat(eb + 2, FLOG2, W, cnt, rk, rw);
                if (q.w) scat(eb + 3, FLOG2, W, cnt, rk, rw);
            } else if (mode == 0) {
                unsigned w4[4] = {q.x, q.y, q.z, q.w};
                int eb = i16 << 4;
                for (int tt = 0; tt < 4; ++tt) {
                    unsigned x = w4[tt];
                    if (!x) continue;
                    for (int bb = 0; bb < 4; ++bb)
                        if ((x >> (8 * bb)) & 0xFFu)
                            scat(eb + tt * 4 + bb, FLOG2, W, cnt, rk, rw);
                }
            } else {
                int eb = i16 << 1;
                if (q.x | q.y) scat(eb + 0, FLOG2, W, cnt, rk, rw);
                if (q.z | q.w) scat(eb + 1, FLOG2, W, cnt, rk, rw);
            }
        }
    }
}

// ---------------------------------------------------------------------------
// Layer-1 row: sorts its own list in LDS (deterministic), batch-major.
// fp16 xT in, fp16 h1 out. Thread l owns batch elements l*8..l*8+7.
// ---------------------------------------------------------------------------
__device__ __forceinline__ void layer1_row(int j, const _Float16* __restrict__ xT,
                                           const float* __restrict__ b1,
                                           const int* __restrict__ cnt,
                                           const int* __restrict__ rk,
                                           const float* __restrict__ rw,
                                           _Float16* __restrict__ h1T) {
    int c = cnt[j]; if (c > CAP) c = CAP;
    if (c == 0) return;

    __shared__ int   ci[CAP];
    __shared__ float wv[CAP];
    if (threadIdx.x == 0) {
        for (int a = 0; a < c; ++a) { ci[a] = rk[(size_t)j * CAP + a]; wv[a] = rw[(size_t)j * CAP + a]; }
        for (int a = 1; a < c; ++a) {               // insertion sort -> deterministic order
            int k = ci[a]; float w = wv[a]; int b = a - 1;
            while (b >= 0 && ci[b] > k) { ci[b + 1] = ci[b]; wv[b + 1] = wv[b]; --b; }
            ci[b + 1] = k; wv[b + 1] = w;
        }
    }
    __syncthreads();

    const float base = b1[j];
    const int l = threadIdx.x;
    float acc[8];
    #pragma unroll
    for (int i = 0; i < 8; ++i) acc[i] = base;

    for (int e = 0; e < c; ++e) {
        float w = wv[e];
        half8 v = ((const half8*)(xT + (size_t)ci[e] * BATCH))[l];
        #pragma unroll
        for (int i = 0; i < 8; ++i) acc[i] += w * (float)v[i];
    }

    half8 o;
    #pragma unroll
    for (int i = 0; i < 8; ++i) o[i] = (_Float16)tanhf(acc[i]);
    ((half8*)(h1T + (size_t)j * BATCH))[l] = o;
}

// In-place global insertion sort of one row list (1 thread per row).
__device__ __forceinline__ void sort_row_global(int j, const int* cnt, int* rk, float* rw) {
    int c = cnt[j]; if (c > CAP) c = CAP;
    if (c <= 1) return;
    int* K = rk + (size_t)j * CAP; float* W_ = rw + (size_t)j * CAP;
    for (int a = 1; a < c; ++a) {
        int k = K[a]; float w = W_[a]; int b = a - 1;
        while (b >= 0 && K[b] > k) { K[b + 1] = K[b]; W_[b + 1] = W_[b]; --b; }
        K[b + 1] = k; W_[b + 1] = w;
    }
}

// ---------------------------------------------------------------------------
// K1: m1 flat scan ∥ x-transpose (nt fp32 read -> fp16 xT) ∥ tanh-bias tables.
// ---------------------------------------------------------------------------
__global__ __launch_bounds__(256) void k1_kernel(const void* __restrict__ m1, const float* __restrict__ W1,
                          const float* __restrict__ x,
                          const float* __restrict__ b1, const float* __restrict__ b2,
                          const unsigned* __restrict__ det,
                          int* __restrict__ cnt1, int* __restrict__ rk1, float* __restrict__ rw1,
                          float* __restrict__ tb1, float* __restrict__ tb2,
                          _Float16* __restrict__ xT) {
    const int bid = blockIdx.x;
    if (bid < MAXC1) {
        const int mode = decide_mode(det);
        const int nc = (int)(((size_t)D1 * D0 * esize_of(mode)) >> 17);
        if (bid < nc) scan_chunk<12>(m1, W1, bid, mode, cnt1, rk1, rw1);
    } else if (bid < MAXC1 + (D0 / 32) * (BATCH / 32)) {
        __shared__ float tile[32][33];
        const int t = bid - MAXC1;
        const int cx = t & 127, ry = t >> 7;
        const int tx = threadIdx.x & 31, ty = threadIdx.x >> 5;
        const int c0 = cx * 32, r0 = ry * 32;
        for (int i = ty; i < 32; i += 8)
            tile[i][tx] = __builtin_nontemporal_load(&x[(size_t)(r0 + i) * D0 + c0 + tx]);
        __syncthreads();
        for (int i = ty; i < 32; i += 8)
            xT[(size_t)(c0 + i) * BATCH + r0 + tx] = (_Float16)tile[tx][i];
    } else {
        int tid = (bid - MAXC1 - (D0 / 32) * (BATCH / 32)) * 256 + threadIdx.x;
        if (tid < D1) tb1[tid] = tanhf(b1[tid]);
        else if (tid < D1 + D2) tb2[tid - D1] = tanhf(b2[tid - D1]);
    }
}

// ---------------------------------------------------------------------------
// K2: m2 + m3 flat scans ∥ layer-1 (fp16 xT -> fp16 h1T).
// ---------------------------------------------------------------------------
__global__ __launch_bounds__(256) void k2_kernel(const void* __restrict__ m2, const float* __restrict__ W2,
                          const void* __restrict__ m3, const float* __restrict__ W3,
                          const unsigned* __restrict__ det,
                          int* __restrict__ cnt2, int* __restrict__ rk2, float* __restrict__ rw2,
                          int* __restrict__ cnt3, int* __restrict__ rk3, float* __restrict__ rw3,
                          const _Float16* __restrict__ xT, const float* __restrict__ b1,
                          const int* __restrict__ cnt1, const int* __restrict__ rk1,
                          const float* __restrict__ rw1,
                          _Float16* __restrict__ h1T) {
    const int bid = blockIdx.x;
    if (bid < MAXC2) {
        const int mode = decide_mode(det);
        const int nc = (int)(((size_t)D2 * D1 * esize_of(mode)) >> 17);
        if (bid < nc) scan_chunk<13>(m2, W2, bid, mode, cnt2, rk2, rw2);
    } else if (bid < MAXC2 + MAXC3) {
        const int mode = decide_mode(det);
        const int nc = (int)(((size_t)D3 * D2 * esize_of(mode)) >> 17);
        const int ch = bid - MAXC2;
        if (ch < nc) scan_chunk<13>(m3, W3, ch, mode, cnt3, rk3, rw3);
    } else {
        layer1_row(bid - MAXC2 - MAXC3, xT, b1, cnt1, rk1, rw1, h1T);
    }
}

// K3: tiny sort pass — rk2 (8192 rows) + rk3 (4096 rows), 1 thread/row.
__global__ __launch_bounds__(256) void sort23_kernel(const int* __restrict__ cnt2,
                          int* __restrict__ rk2, float* __restrict__ rw2,
                          const int* __restrict__ cnt3,
                          int* __restrict__ rk3, float* __restrict__ rw3) {
    int r = blockIdx.x * 256 + threadIdx.x;
    if (r < RP) sort_row_global(r, cnt2, rk2, rw2);
    else if (r < RP + D3) sort_row_global(r - RP, cnt3, rk3, rw3);
}

// ---------------------------------------------------------------------------
// K4: fused layer-2 + layer-3 + output transpose. Block (32,8): 32j x 32b tile.
// h2 values computed on the fly from h1 (recompute factor ~1.25, L2/L3-hot).
// All lists pre-sorted -> deterministic summation everywhere.
// ---------------------------------------------------------------------------
__global__ void l3t_kernel(const _Float16* __restrict__ h1T,
                           const float* __restrict__ b2, const float* __restrict__ b3,
                           const float* __restrict__ tb1, const float* __restrict__ tb2,
                           const int* __restrict__ cnt1, const int* __restrict__ cnt2,
                           const int* __restrict__ rk2, const float* __restrict__ rw2,
                           const int* __restrict__ c3, const int* __restrict__ k3,
                           const float* __restrict__ w3,
                           float* __restrict__ out) {
    __shared__ float tile[32][33];
    const int j0 = blockIdx.x * 32, b0 = blockIdx.y * 32;
    const int tx = threadIdx.x, ty = threadIdx.y;

    for (int s = 0; s < 4; ++s) {
        int jl = ty + 8 * s;
        int j = j0 + jl;
        float acc = b3[j];
        int c = c3[j]; if (c > CAP) c = CAP;
        const int* kk = k3 + (size_t)j * CAP;
        const float* ww = w3 + (size_t)j * CAP;
        for (int e = 0; e < c; ++e) {
            int k2 = kk[e];
            float w = ww[e];
            float hv;
            int c2 = cnt2[k2]; if (c2 > CAP) c2 = CAP;
            if (c2 == 0) {
                hv = tb2[k2];
            } else {
                float a2 = b2[k2];
                const int* kk2 = rk2 + (size_t)k2 * CAP;
                const float* ww2 = rw2 + (size_t)k2 * CAP;
                for (int e2 = 0; e2 < c2; ++e2) {
                    int k1 = kk2[e2];
                    float w2 = ww2[e2];
                    a2 += w2 * (cnt1[k1] ? (float)h1T[(size_t)k1 * BATCH + b0 + tx]
                                         : tb1[k1]);
                }
                hv = tanhf(a2);
            }
            acc += w * hv;
        }
        tile[jl][tx] = acc;
    }
    __syncthreads();
    for (int s = 0; s < 4; ++s) {
        int bl = ty + 8 * s;
        __builtin_nontemporal_store(tile[tx][bl], &out[(size_t)(b0 + bl) * D3 + j0 + tx]);
    }
}

// ---------------------------------------------------------------------------
// Fallback path (ws too small): flat scans + global sort + chained evaluation.
// ---------------------------------------------------------------------------
__global__ __launch_bounds__(256) void scan1_kernel(const void* m, const float* W, const unsigned* det,
                                                    int* cnt, int* rk, float* rw) {
    const int mode = decide_mode(det);
    const int nc = (int)(((size_t)D1 * D0 * esize_of(mode)) >> 17);
    if (blockIdx.x < (unsigned)nc) scan_chunk<12>(m, W, blockIdx.x, mode, cnt, rk, rw);
}
__global__ __launch_bounds__(256) void scan2_kernel(const void* m, const float* W, const unsigned* det,
                                                    int* cnt, int* rk, float* rw) {
    const int mode = decide_mode(det);
    const int nc = (int)(((size_t)D2 * D1 * esize_of(mode)) >> 17);
    if (blockIdx.x < (unsigned)nc) scan_chunk<13>(m, W, blockIdx.x, mode, cnt, rk, rw);
}
__global__ __launch_bounds__(256) void scan3_kernel(const void* m, const float* W, const unsigned* det,
                                                    int* cnt, int* rk, float* rw) {
    const int mode = decide_mode(det);
    const int nc = (int)(((size_t)D3 * D2 * esize_of(mode)) >> 17);
    if (blockIdx.x < (unsigned)nc) scan_chunk<13>(m, W, blockIdx.x, mode, cnt, rk, rw);
}
__global__ __launch_bounds__(256) void sortall_kernel(const int* cnt, int* rk, float* rw) {
    int r = blockIdx.x * 256 + threadIdx.x;          // rows of the 3 concatenated lists
    if (r < 3 * RP) sort_row_global(r, cnt, rk, rw);
}

__global__ void out_kernel(const float* __restrict__ x,
                           const float* __restrict__ b1, const float* __restrict__ b2,
                           const float* __restrict__ b3,
                           const int* __restrict__ c1, const int* __restrict__ k1, const float* __restrict__ w1,
                           const int* __restrict__ c2, const int* __restrict__ k2, const float* __restrict__ w2,
                           const int* __restrict__ c3, const int* __restrict__ k3, const float* __restrict__ w3,
                           float* __restrict__ out) {
    int idx = blockIdx.x * blockDim.x + threadIdx.x;
    if (idx >= BATCH * D3) return;
    int b = idx >> 12, j = idx & 4095;
    float acc = b3[j];
    int c = c3[j]; if (c > CAP) c = CAP;
    for (int e = 0; e < c; ++e) {
        int kk2 = k3[(size_t)j * CAP + e];
        float a2 = b2[kk2];
        int cc2 = c2[kk2]; if (cc2 > CAP) cc2 = CAP;
        for (int e2 = 0; e2 < cc2; ++e2) {
            int kk1 = k2[(size_t)kk2 * CAP + e2];
            float a1 = b1[kk1];
            int cc1 = c1[kk1]; if (cc1 > CAP) cc1 = CAP;
            for (int e1 = 0; e1 < cc1; ++e1)
                a1 += w1[(size_t)kk1 * CAP + e1] * x[(size_t)b * D0 + k1[(size_t)kk1 * CAP + e1]];
            a2 += w2[(size_t)kk2 * CAP + e2] * tanhf(a1);
        }
        acc += w3[(size_t)j * CAP + e] * tanhf(a2);
    }
    out[idx] = acc;
}

extern "C" void kernel_launch(void* const* d_in, const int* in_sizes, int n_in,
                              void* d_out, int out_size, void* d_ws, size_t ws_size,
                              hipStream_t stream) {
    const float* x  = (const float*)d_in[0];
    const float* W1 = (const float*)d_in[1];
    const float* b1 = (const float*)d_in[2];
    const void*  m1 = d_in[3];
    const float* W2 = (const float*)d_in[4];
    const float* b2 = (const float*)d_in[5];
    const void*  m2 = d_in[6];
    const float* W3 = (const float*)d_in[7];
    const float* b3 = (const float*)d_in[8];
    const void*  m3 = d_in[9];

    uint8_t* ws = (uint8_t*)d_ws;
    unsigned* det = (unsigned*)(ws + OFF_DET);
    int* cnt1 = (int*)(ws + OFF_CNT);
    int* cnt2 = cnt1 + RP;
    int* cnt3 = cnt2 + RP;
    float* tb1 = (float*)(ws + OFF_TB);
    float* tb2 = tb1 + RP;
    int* rk1 = (int*)(ws + OFF_RK);
    int* rk2 = rk1 + (size_t)RP * CAP;
    int* rk3 = rk2 + (size_t)RP * CAP;
    float* rw1 = (float*)(ws + OFF_RW);
    float* rw2 = rw1 + (size_t)RP * CAP;
    float* rw3 = rw2 + (size_t)RP * CAP;
    _Float16* xT  = (_Float16*)(ws + OFF_XT);
    _Float16* h1T = (_Float16*)(ws + OFF_H1);

    hipMemsetAsync(ws, 0, ZERO_BYTES, stream);       // det + cnt (atomics accumulate otherwise)
    detect_kernel<<<1024, 256, 0, stream>>>((const uint8_t*)m1, det);

    if (ws_size >= WS_BIG) {
        const int K1_BLOCKS = MAXC1 + (D0 / 32) * (BATCH / 32) + (D1 + D2) / 256;   // 10304
        k1_kernel<<<K1_BLOCKS, 256, 0, stream>>>(
            m1, W1, x, b1, b2, det, cnt1, rk1, rw1, tb1, tb2, xT);

        const int K2_BLOCKS = MAXC2 + MAXC3 + D1;                                   // 14336
        k2_kernel<<<K2_BLOCKS, 256, 0, stream>>>(
            m2, W2, m3, W3, det,
            cnt2, rk2, rw2, cnt3, rk3, rw3,
            xT, b1, cnt1, rk1, rw1, h1T);

        sort23_kernel<<<(RP + D3) / 256, 256, 0, stream>>>(
            cnt2, rk2, rw2, cnt3, rk3, rw3);

        l3t_kernel<<<dim3(D3 / 32, BATCH / 32), dim3(32, 8), 0, stream>>>(
            h1T, b2, b3, tb1, tb2, cnt1, cnt2, rk2, rw2,
            cnt3, rk3, rw3, (float*)d_out);
    } else {
        scan1_kernel<<<MAXC1, 256, 0, stream>>>(m1, W1, det, cnt1, rk1, rw1);
        scan2_kernel<<<MAXC2, 256, 0, stream>>>(m2, W2, det, cnt2, rk2, rw2);
        scan3_kernel<<<MAXC3, 256, 0, stream>>>(m3, W3, det, cnt3, rk3, rw3);
        sortall_kernel<<<3 * RP / 256, 256, 0, stream>>>(cnt1, rk1, rw1);  // cnt/rk/rw contiguous x3
        out_kernel<<<(BATCH * D3 + 255) / 256, 256, 0, stream>>>(
            x, b1, b2, b3,
            cnt1, rk1, rw1, cnt2, rk2, rw2, cnt3, rk3, rw3,
            (float*)d_out);
    }
}

// Round 13
// 167.072 us; speedup vs baseline: 1.0452x; 1.0452x over previous
//
#include <hip/hip_runtime.h>
#include <stdint.h>

#define CAP 32

typedef unsigned int u32x4 __attribute__((ext_vector_type(4)));
typedef _Float16 half8 __attribute__((ext_vector_type(8)));

static constexpr int BATCH = 2048;
static constexpr int D0 = 4096, D1 = 8192, D2 = 8192, D3 = 4096;
static constexpr int RP = 8192;
static constexpr size_t PREFIX_BYTES = 8u << 20;   // detect prefix

static constexpr int CHUNK16 = 8192;               // u32x4 per 128 KiB chunk
// worst-case (int64 masks) chunk counts — grid sized for these, extra blocks exit
static constexpr int MAXC1 = 2048, MAXC2 = 4096, MAXC3 = 2048;

// ---------------- ws layout (bytes) ----------------
static constexpr size_t OFF_DET   = 0;                               // 2 u32
static constexpr size_t OFF_REFD2 = 256;                             // 8192 int
static constexpr size_t OFF_CNT   = OFF_REFD2 + (size_t)RP * 4;      // 3*8192 int (atomic -> zero each call)
static constexpr size_t ZERO_BYTES= OFF_CNT + 3ull * RP * 4;         // det+refd2+cnt
static constexpr size_t OFF_TB    = ZERO_BYTES;                      // 2*8192 float
static constexpr size_t OFF_RK    = OFF_TB + 2ull * RP * 4;          // 3*8192*CAP int
static constexpr size_t OFF_RW    = OFF_RK + 3ull * RP * CAP * 4;
static constexpr size_t OFF_XT    = OFF_RW + 3ull * RP * CAP * 4;    // float [4096][2048]
static constexpr size_t OFF_H1    = OFF_XT + (size_t)D0 * BATCH * 4; // half  [8192][2048]
static constexpr size_t OFF_H2    = OFF_H1 + (size_t)D1 * BATCH * 2; // half  [8192][2048]
static constexpr size_t WS_BIG    = OFF_H2 + (size_t)D2 * BATCH * 2; // ~104 MB

__device__ __forceinline__ u32x4 ntload4(const u32x4* p) {
    return __builtin_nontemporal_load(p);
}

// ---------------------------------------------------------------------------
// Mask dtype detection (nonzero-byte position stats over 8MB prefix of m1).
// ---------------------------------------------------------------------------
__global__ __launch_bounds__(256) void detect_kernel(const uint8_t* __restrict__ m,
                                                     unsigned* __restrict__ det) {
    const u32x4* p = (const u32x4*)m;
    const int n16 = (int)(PREFIX_BYTES / 16);
    unsigned c123 = 0, c4 = 0;
    for (int i = blockIdx.x * blockDim.x + threadIdx.x; i < n16; i += gridDim.x * blockDim.x) {
        u32x4 q = ntload4(p + i);
        if ((q.x | q.y | q.z | q.w) == 0u) continue;
        unsigned w4[4] = {q.x, q.y, q.z, q.w};
        for (int t = 0; t < 4; ++t) {
            unsigned v = w4[t];
            if (!v) continue;
            for (int bb = 0; bb < 4; ++bb) {
                if ((v >> (8 * bb)) & 0xFFu) {
                    int pm8 = (t * 4 + bb) & 7;
                    if (pm8 & 3) c123++;
                    else if (pm8 == 4) c4++;
                }
            }
        }
    }
    if (c123) atomicAdd(&det[0], c123);
    if (c4)   atomicAdd(&det[1], c4);
}

__device__ __forceinline__ int decide_mode(const unsigned* det) {
    unsigned c123 = det[0], c4 = det[1];
    if (c123 > 520u) return 0;           // 1-byte elements
    if (c123 > 200u) return 1;           // float32 (word != 0 works)
    return (c4 > 40u) ? 1 : 2;           // int32 vs int64
}

__device__ __forceinline__ int esize_of(int mode) { return mode == 0 ? 1 : (mode == 1 ? 4 : 8); }

// ---------------------------------------------------------------------------
// Barrier-free flat chunk scan. Block scans one contiguous 128 KiB chunk with
// 4 iters x 8 hoisted nt loads. Nonzero element e -> global atomic scatter.
// Lists are UNSORTED; consumers sort at point of use (determinism).
// ---------------------------------------------------------------------------
__device__ __forceinline__ void scat(int e, int flog2, const float* W,
                                     int* cnt, int* rk, float* rw, int* mark) {
    int row = e >> flog2;
    int col = e & ((1 << flog2) - 1);
    int pos = atomicAdd(&cnt[row], 1);
    if (pos < CAP) {
        rk[(size_t)row * CAP + pos] = col;
        rw[(size_t)row * CAP + pos] = W[(size_t)e];
    }
    if (mark) atomicOr(&mark[col], 1);
}

template<int FLOG2>
__device__ __forceinline__ void scan_chunk(const void* __restrict__ mask, const float* __restrict__ W,
                                           int chunk, int mode,
                                           int* cnt, int* rk, float* rw, int* mark) {
    const u32x4* q4 = (const u32x4*)mask;
    const int base16 = chunk * CHUNK16;
    #pragma unroll 1
    for (int it = 0; it < 4; ++it) {
        const u32x4* p = q4 + base16 + it * 2048 + threadIdx.x;
        u32x4 v[8];
        #pragma unroll
        for (int t = 0; t < 8; ++t) v[t] = ntload4(p + t * 256);
        #pragma unroll
        for (int t = 0; t < 8; ++t) {
            u32x4 q = v[t];
            if ((q.x | q.y | q.z | q.w) == 0u) continue;
            int i16 = base16 + it * 2048 + t * 256 + (int)threadIdx.x;
            if (mode == 1) {
                int eb = i16 << 2;
                if (q.x) scat(eb + 0, FLOG2, W, cnt, rk, rw, mark);
                if (q.y) scat(eb + 1, FLOG2, W, cnt, rk, rw, mark);
                if (q.z) scat(eb + 2, FLOG2, W, cnt, rk, rw, mark);
                if (q.w) scat(eb + 3, FLOG2, W, cnt, rk, rw, mark);
            } else if (mode == 0) {
                unsigned w4[4] = {q.x, q.y, q.z, q.w};
                int eb = i16 << 4;
                for (int tt = 0; tt < 4; ++tt) {
                    unsigned x = w4[tt];
                    if (!x) continue;
                    for (int bb = 0; bb < 4; ++bb)
                        if ((x >> (8 * bb)) & 0xFFu)
                            scat(eb + tt * 4 + bb, FLOG2, W, cnt, rk, rw, mark);
                }
            } else {
                int eb = i16 << 1;
                if (q.x | q.y) scat(eb + 0, FLOG2, W, cnt, rk, rw, mark);
                if (q.z | q.w) scat(eb + 1, FLOG2, W, cnt, rk, rw, mark);
            }
        }
    }
}

// ---------------------------------------------------------------------------
// Sparse layer row: sorts its own list in LDS (deterministic), batch-major.
// Thread l owns batch elements l*8..l*8+7. Output stored fp16.
// ---------------------------------------------------------------------------
template<bool HAS_TB, bool USE_REFD, bool IN_HALF>
__device__ __forceinline__ void layer_row(int j, const void* __restrict__ inT,
                                          const float* __restrict__ bias,
                                          const float* __restrict__ tb_in,
                                          const int* __restrict__ cnt_in,
                                          const int* __restrict__ cnt,
                                          const int* __restrict__ rk,
                                          const float* __restrict__ rw,
                                          const int* __restrict__ refd,
                                          _Float16* __restrict__ outT) {
    int c = cnt[j]; if (c > CAP) c = CAP;
    if (c == 0) return;
    if (USE_REFD && refd[j] == 0) return;

    __shared__ int   ci[CAP];
    __shared__ float wv[CAP];
    if (threadIdx.x == 0) {
        for (int a = 0; a < c; ++a) { ci[a] = rk[(size_t)j * CAP + a]; wv[a] = rw[(size_t)j * CAP + a]; }
        for (int a = 1; a < c; ++a) {               // insertion sort -> deterministic order
            int k = ci[a]; float w = wv[a]; int b = a - 1;
            while (b >= 0 && ci[b] > k) { ci[b + 1] = ci[b]; wv[b + 1] = wv[b]; --b; }
            ci[b + 1] = k; wv[b + 1] = w;
        }
    }
    __syncthreads();

    float base = bias[j];
    if (HAS_TB)
        for (int e = 0; e < c; ++e)
            if (cnt_in[ci[e]] == 0) base += wv[e] * tb_in[ci[e]];   // inactive input: constant

    const int l = threadIdx.x;
    float acc[8];
    #pragma unroll
    for (int i = 0; i < 8; ++i) acc[i] = base;

    for (int e = 0; e < c; ++e) {
        int k = ci[e];
        if (HAS_TB && cnt_in[k] == 0) continue;
        float w = wv[e];
        if (IN_HALF) {
            half8 v = ((const half8*)((const _Float16*)inT + (size_t)k * BATCH))[l];
            #pragma unroll
            for (int i = 0; i < 8; ++i) acc[i] += w * (float)v[i];
        } else {
            const float* row = (const float*)inT + (size_t)k * BATCH + l * 8;
            float4 v0 = *(const float4*)row;
            float4 v1 = *(const float4*)(row + 4);
            acc[0] += w * v0.x; acc[1] += w * v0.y; acc[2] += w * v0.z; acc[3] += w * v0.w;
            acc[4] += w * v1.x; acc[5] += w * v1.y; acc[6] += w * v1.z; acc[7] += w * v1.w;
        }
    }

    half8 o;
    #pragma unroll
    for (int i = 0; i < 8; ++i) o[i] = (_Float16)tanhf(acc[i]);
    ((half8*)(outT + (size_t)j * BATCH))[l] = o;
}

// In-place global insertion sort of one row list (1 thread per row).
__device__ __forceinline__ void sort_row_global(int j, const int* cnt, int* rk, float* rw) {
    int c = cnt[j]; if (c > CAP) c = CAP;
    if (c <= 1) return;
    int* K = rk + (size_t)j * CAP; float* W_ = rw + (size_t)j * CAP;
    for (int a = 1; a < c; ++a) {
        int k = K[a]; float w = W_[a]; int b = a - 1;
        while (b >= 0 && K[b] > k) { K[b + 1] = K[b]; W_[b + 1] = W_[b]; --b; }
        K[b + 1] = k; W_[b + 1] = w;
    }
}

// ---------------------------------------------------------------------------
// K1: m1 flat scan ∥ x-transpose (nt read) ∥ tanh-bias tables.
// blocks: [0,MAXC1) scan; [MAXC1, MAXC1+8192) xpose; then 64 tb blocks.
// ---------------------------------------------------------------------------
__global__ __launch_bounds__(256) void k1_kernel(const void* __restrict__ m1, const float* __restrict__ W1,
                          const float* __restrict__ x,
                          const float* __restrict__ b1, const float* __restrict__ b2,
                          const unsigned* __restrict__ det,
                          int* __restrict__ cnt1, int* __restrict__ rk1, float* __restrict__ rw1,
                          float* __restrict__ tb1, float* __restrict__ tb2,
                          float* __restrict__ xT) {
    const int bid = blockIdx.x;
    if (bid < MAXC1) {
        const int mode = decide_mode(det);
        const int nc = (int)(((size_t)D1 * D0 * esize_of(mode)) >> 17);
        if (bid < nc) scan_chunk<12>(m1, W1, bid, mode, cnt1, rk1, rw1, nullptr);
    } else if (bid < MAXC1 + (D0 / 32) * (BATCH / 32)) {
        __shared__ float tile[32][33];
        const int t = bid - MAXC1;
        const int cx = t & 127, ry = t >> 7;
        const int tx = threadIdx.x & 31, ty = threadIdx.x >> 5;
        const int c0 = cx * 32, r0 = ry * 32;
        for (int i = ty; i < 32; i += 8)
            tile[i][tx] = __builtin_nontemporal_load(&x[(size_t)(r0 + i) * D0 + c0 + tx]);
        __syncthreads();
        for (int i = ty; i < 32; i += 8)
            xT[(size_t)(c0 + i) * BATCH + r0 + tx] = tile[tx][i];
    } else {
        int tid = (bid - MAXC1 - (D0 / 32) * (BATCH / 32)) * 256 + threadIdx.x;
        if (tid < D1) tb1[tid] = tanhf(b1[tid]);
        else if (tid < D1 + D2) tb2[tid - D1] = tanhf(b2[tid - D1]);
    }
}

// ---------------------------------------------------------------------------
// K2: m2 + m3 flat scans (m3 marks refd2) ∥ layer-1 (fp32 xT -> fp16 h1T).
// blocks: [0,MAXC2) m2; [MAXC2,MAXC2+MAXC3) m3; then 8192 layer-1 rows.
// ---------------------------------------------------------------------------
__global__ __launch_bounds__(256) void k2_kernel(const void* __restrict__ m2, const float* __restrict__ W2,
                          const void* __restrict__ m3, const float* __restrict__ W3,
                          const unsigned* __restrict__ det,
                          int* __restrict__ cnt2, int* __restrict__ rk2, float* __restrict__ rw2,
                          int* __restrict__ cnt3, int* __restrict__ rk3, float* __restrict__ rw3,
                          int* __restrict__ refd2,
                          const float* __restrict__ xT, const float* __restrict__ b1,
                          const int* __restrict__ cnt1, const int* __restrict__ rk1,
                          const float* __restrict__ rw1,
                          _Float16* __restrict__ h1T) {
    const int bid = blockIdx.x;
    if (bid < MAXC2) {
        const int mode = decide_mode(det);
        const int nc = (int)(((size_t)D2 * D1 * esize_of(mode)) >> 17);
        if (bid < nc) scan_chunk<13>(m2, W2, bid, mode, cnt2, rk2, rw2, nullptr);
    } else if (bid < MAXC2 + MAXC3) {
        const int mode = decide_mode(det);
        const int nc = (int)(((size_t)D3 * D2 * esize_of(mode)) >> 17);
        const int ch = bid - MAXC2;
        if (ch < nc) scan_chunk<13>(m3, W3, ch, mode, cnt3, rk3, rw3, refd2);
    } else {
        layer_row<false, false, false>(bid - MAXC2 - MAXC3, xT, b1, nullptr, nullptr,
                                       cnt1, rk1, rw1, nullptr, h1T);
    }
}

// K3: layer-2 (fp16 h1T -> fp16 h2T, refd2-filtered) ∥ sort rk3 lists.
__global__ __launch_bounds__(256) void k3_kernel(const _Float16* __restrict__ h1T, const float* __restrict__ b2,
                          const float* __restrict__ tb1, const int* __restrict__ cnt1,
                          const int* __restrict__ cnt2, const int* __restrict__ rk2,
                          const float* __restrict__ rw2, const int* __restrict__ refd2,
                          _Float16* __restrict__ h2T,
                          const int* __restrict__ cnt3, int* __restrict__ rk3, float* __restrict__ rw3) {
    const int bid = blockIdx.x;
    if (bid < D2) {
        layer_row<true, true, true>(bid, h1T, b2, tb1, cnt1, cnt2, rk2, rw2, refd2, h2T);
    } else {
        int j = (bid - D2) * 256 + threadIdx.x;
        if (j < D3) sort_row_global(j, cnt3, rk3, rw3);
    }
}

// ---------------------------------------------------------------------------
// K4: fused layer-3 + output transpose (fp16 h2T reads, nt fp32 out stores).
// ---------------------------------------------------------------------------
__global__ void l3t_kernel(const _Float16* __restrict__ h2T,
                           const float* __restrict__ b3, const float* __restrict__ tb2,
                           const int* __restrict__ cnt2,
                           const int* __restrict__ c3, const int* __restrict__ k3,
                           const float* __restrict__ w3,
                           float* __restrict__ out) {
    __shared__ float tile[32][33];
    const int j0 = blockIdx.x * 32, b0 = blockIdx.y * 32;
    const int tx = threadIdx.x, ty = threadIdx.y;

    for (int s = 0; s < 4; ++s) {
        int jl = ty + 8 * s;
        int j = j0 + jl;
        float acc = b3[j];
        int c = c3[j]; if (c > CAP) c = CAP;
        const int* kk = k3 + (size_t)j * CAP;
        const float* ww = w3 + (size_t)j * CAP;
        for (int e = 0; e < c; ++e) {
            int k = kk[e];
            float w = ww[e];
            acc += w * (cnt2[k] ? (float)h2T[(size_t)k * BATCH + b0 + tx] : tb2[k]);
        }
        tile[jl][tx] = acc;
    }
    __syncthreads();
    for (int s = 0; s < 4; ++s) {
        int bl = ty + 8 * s;
        __builtin_nontemporal_store(tile[tx][bl], &out[(size_t)(b0 + bl) * D3 + j0 + tx]);
    }
}

// ---------------------------------------------------------------------------
// Fallback path (ws too small for big buffers): flat scans + global sort +
// chained per-(b,j) evaluation.
// ---------------------------------------------------------------------------
__global__ __launch_bounds__(256) void scan1_kernel(const void* m, const float* W, const unsigned* det,
                                                    int* cnt, int* rk, float* rw) {
    const int mode = decide_mode(det);
    const int nc = (int)(((size_t)D1 * D0 * esize_of(mode)) >> 17);
    if (blockIdx.x < (unsigned)nc) scan_chunk<12>(m, W, blockIdx.x, mode, cnt, rk, rw, nullptr);
}
__global__ __launch_bounds__(256) void scan2_kernel(const void* m, const float* W, const unsigned* det,
                                                    int* cnt, int* rk, float* rw) {
    const int mode = decide_mode(det);
    const int nc = (int)(((size_t)D2 * D1 * esize_of(mode)) >> 17);
    if (blockIdx.x < (unsigned)nc) scan_chunk<13>(m, W, blockIdx.x, mode, cnt, rk, rw, nullptr);
}
__global__ __launch_bounds__(256) void scan3_kernel(const void* m, const float* W, const unsigned* det,
                                                    int* cnt, int* rk, float* rw) {
    const int mode = decide_mode(det);
    const int nc = (int)(((size_t)D3 * D2 * esize_of(mode)) >> 17);
    if (blockIdx.x < (unsigned)nc) scan_chunk<13>(m, W, blockIdx.x, mode, cnt, rk, rw, nullptr);
}
__global__ __launch_bounds__(256) void sortall_kernel(const int* cnt, int* rk, float* rw) {
    int r = blockIdx.x * 256 + threadIdx.x;          // rows of the 3 concatenated lists
    if (r < 3 * RP) sort_row_global(r, cnt, rk, rw);
}

__global__ void out_kernel(const float* __restrict__ x,
                           const float* __restrict__ b1, const float* __restrict__ b2,
                           const float* __restrict__ b3,
                           const int* __restrict__ c1, const int* __restrict__ k1, const float* __restrict__ w1,
                           const int* __restrict__ c2, const int* __restrict__ k2, const float* __restrict__ w2,
                           const int* __restrict__ c3, const int* __restrict__ k3, const float* __restrict__ w3,
                           float* __restrict__ out) {
    int idx = blockIdx.x * blockDim.x + threadIdx.x;
    if (idx >= BATCH * D3) return;
    int b = idx >> 12, j = idx & 4095;
    float acc = b3[j];
    int c = c3[j]; if (c > CAP) c = CAP;
    for (int e = 0; e < c; ++e) {
        int kk2 = k3[(size_t)j * CAP + e];
        float a2 = b2[kk2];
        int cc2 = c2[kk2]; if (cc2 > CAP) cc2 = CAP;
        for (int e2 = 0; e2 < cc2; ++e2) {
            int kk1 = k2[(size_t)kk2 * CAP + e2];
            float a1 = b1[kk1];
            int cc1 = c1[kk1]; if (cc1 > CAP) cc1 = CAP;
            for (int e1 = 0; e1 < cc1; ++e1)
                a1 += w1[(size_t)kk1 * CAP + e1] * x[(size_t)b * D0 + k1[(size_t)kk1 * CAP + e1]];
            a2 += w2[(size_t)kk2 * CAP + e2] * tanhf(a1);
        }
        acc += w3[(size_t)j * CAP + e] * tanhf(a2);
    }
    out[idx] = acc;
}

extern "C" void kernel_launch(void* const* d_in, const int* in_sizes, int n_in,
                              void* d_out, int out_size, void* d_ws, size_t ws_size,
                              hipStream_t stream) {
    const float* x  = (const float*)d_in[0];
    const float* W1 = (const float*)d_in[1];
    const float* b1 = (const float*)d_in[2];
    const void*  m1 = d_in[3];
    const float* W2 = (const float*)d_in[4];
    const float* b2 = (const float*)d_in[5];
    const void*  m2 = d_in[6];
    const float* W3 = (const float*)d_in[7];
    const float* b3 = (const float*)d_in[8];
    const void*  m3 = d_in[9];

    uint8_t* ws = (uint8_t*)d_ws;
    unsigned* det = (unsigned*)(ws + OFF_DET);
    int* refd2 = (int*)(ws + OFF_REFD2);
    int* cnt1 = (int*)(ws + OFF_CNT);
    int* cnt2 = cnt1 + RP;
    int* cnt3 = cnt2 + RP;
    float* tb1 = (float*)(ws + OFF_TB);
    float* tb2 = tb1 + RP;
    int* rk1 = (int*)(ws + OFF_RK);
    int* rk2 = rk1 + (size_t)RP * CAP;
    int* rk3 = rk2 + (size_t)RP * CAP;
    float* rw1 = (float*)(ws + OFF_RW);
    float* rw2 = rw1 + (size_t)RP * CAP;
    float* rw3 = rw2 + (size_t)RP * CAP;
    float* xT  = (float*)(ws + OFF_XT);
    _Float16* h1T = (_Float16*)(ws + OFF_H1);
    _Float16* h2T = (_Float16*)(ws + OFF_H2);

    hipMemsetAsync(ws, 0, ZERO_BYTES, stream);       // det + refd2 + cnt (atomics accumulate otherwise)
    detect_kernel<<<1024, 256, 0, stream>>>((const uint8_t*)m1, det);

    if (ws_size >= WS_BIG) {
        const int K1_BLOCKS = MAXC1 + (D0 / 32) * (BATCH / 32) + (D1 + D2) / 256;   // 10304
        k1_kernel<<<K1_BLOCKS, 256, 0, stream>>>(
            m1, W1, x, b1, b2, det, cnt1, rk1, rw1, tb1, tb2, xT);

        const int K2_BLOCKS = MAXC2 + MAXC3 + D1;                                   // 14336
        k2_kernel<<<K2_BLOCKS, 256, 0, stream>>>(
            m2, W2, m3, W3, det,
            cnt2, rk2, rw2, cnt3, rk3, rw3, refd2,
            xT, b1, cnt1, rk1, rw1, h1T);

        k3_kernel<<<D2 + D3 / 256, 256, 0, stream>>>(
            h1T, b2, tb1, cnt1, cnt2, rk2, rw2, refd2, h2T, cnt3, rk3, rw3);

        l3t_kernel<<<dim3(D3 / 32, BATCH / 32), dim3(32, 8), 0, stream>>>(
            h2T, b3, tb2, cnt2, cnt3, rk3, rw3, (float*)d_out);
    } else {
        scan1_kernel<<<MAXC1, 256, 0, stream>>>(m1, W1, det, cnt1, rk1, rw1);
        scan2_kernel<<<MAXC2, 256, 0, stream>>>(m2, W2, det, cnt2, rk2, rw2);
        scan3_kernel<<<MAXC3, 256, 0, stream>>>(m3, W3, det, cnt3, rk3, rw3);
        sortall_kernel<<<3 * RP / 256, 256, 0, stream>>>(cnt1, rk1, rw1);  // cnt/rk/rw contiguous x3
        out_kernel<<<(BATCH * D3 + 255) / 256, 256, 0, stream>>>(
            x, b1, b2, b3,
            cnt1, rk1, rw1, cnt2, rk2, rw2, cnt3, rk3, rw3,
            (float*)d_out);
    }
}